// Round 1
// baseline (3189.475 us; speedup 1.0000x reference)
//
#include <hip/hip_runtime.h>

#define EPS 1e-8f

// ---------------------------------------------------------------------------
// Kernel A: h = x @ W^T (fp32, VALU) fused with per-node score projections
//   s_src[n,head] = sum_d h[n,head,d] * a_src[head,d]   (same for dst)
// Tile: 64 nodes x 64 outs per block (blockIdx.y selects which 64-out half).
// LDS: Wt[128k][64o] transposed (32KB) + xt[128k][64n] transposed (32KB) = 64KB.
// Thread: o4 = t&15 (4 outs), n4g = t>>4 (4 nodes) -> 4x4 register block.
// ---------------------------------------------------------------------------
__global__ __launch_bounds__(256) void gemm_s_kernel(
    const float* __restrict__ x, const float* __restrict__ W,
    const float* __restrict__ a_src, const float* __restrict__ a_dst,
    float* __restrict__ h, float* __restrict__ s_src, float* __restrict__ s_dst,
    int N, int n_tiles)
{
    __shared__ float Wt[128 * 64];  // Wt[k*64 + o']
    __shared__ float xt[128 * 64];  // xt[k*64 + n]

    const int t = threadIdx.x;
    const int half = blockIdx.y;          // 0 or 1: which 64 output columns
    const float* Wh = W + half * 64 * 128;

    // Load W half, transposed. idx bits: [4:0]=o_low, [9:5]=k4, [10]=o_high.
    // LDS write bank = o' % 32 -> lanes span 32 banks (2-way, free).
#pragma unroll
    for (int p = 0; p < 8; ++p) {
        int idx = p * 256 + t;
        int ol = (idx & 31) | ((idx >> 10) << 5);
        int k4 = (idx >> 5) & 31;
        float4 w = *(const float4*)(Wh + ol * 128 + k4 * 4);
        Wt[(4 * k4 + 0) * 64 + ol] = w.x;
        Wt[(4 * k4 + 1) * 64 + ol] = w.y;
        Wt[(4 * k4 + 2) * 64 + ol] = w.z;
        Wt[(4 * k4 + 3) * 64 + ol] = w.w;
    }
    __syncthreads();

    const int o4 = t & 15;    // out group: outs = half*64 + 4*o4 + j
    const int n4g = t >> 4;   // node group: nodes = nbase + 4*n4g + i
    const int head = half * 2 + (o4 >> 3);
    const float4 as = *(const float4*)(a_src + head * 32 + (o4 & 7) * 4);
    const float4 ad = *(const float4*)(a_dst + head * 32 + (o4 & 7) * 4);

    for (int tile = blockIdx.x; tile < n_tiles; tile += gridDim.x) {
        const int nbase = tile * 64;
        __syncthreads();  // protect xt from previous iteration's readers
        // Load x tile transposed. idx bits: [5:0]=n, [10:6]=k4.
#pragma unroll
        for (int p = 0; p < 8; ++p) {
            int idx = p * 256 + t;
            int n = idx & 63;
            int k4 = idx >> 6;
            int ng = nbase + n;
            float4 v = make_float4(0.f, 0.f, 0.f, 0.f);
            if (ng < N) v = *(const float4*)(x + (size_t)ng * 128 + k4 * 4);
            xt[(4 * k4 + 0) * 64 + n] = v.x;
            xt[(4 * k4 + 1) * 64 + n] = v.y;
            xt[(4 * k4 + 2) * 64 + n] = v.z;
            xt[(4 * k4 + 3) * 64 + n] = v.w;
        }
        __syncthreads();

        float acc[4][4];
#pragma unroll
        for (int i = 0; i < 4; ++i)
#pragma unroll
            for (int j = 0; j < 4; ++j) acc[i][j] = 0.f;

        for (int k = 0; k < 128; ++k) {
            float4 wv = *(const float4*)(Wt + k * 64 + 4 * o4);   // broadcast, conflict-free
            float4 xv = *(const float4*)(xt + k * 64 + 4 * n4g);  // broadcast
            float wa[4] = {wv.x, wv.y, wv.z, wv.w};
            float xa[4] = {xv.x, xv.y, xv.z, xv.w};
#pragma unroll
            for (int i = 0; i < 4; ++i)
#pragma unroll
                for (int j = 0; j < 4; ++j) acc[i][j] += xa[i] * wa[j];
        }

        // Epilogue: write h tile + reduced score projections
#pragma unroll
        for (int i = 0; i < 4; ++i) {
            int n = nbase + 4 * n4g + i;
            float ps = acc[i][0] * as.x + acc[i][1] * as.y + acc[i][2] * as.z + acc[i][3] * as.w;
            float pd = acc[i][0] * ad.x + acc[i][1] * ad.y + acc[i][2] * ad.z + acc[i][3] * ad.w;
            // reduce across the 8 o4-lanes belonging to this head (t bits 0..2)
            ps += __shfl_xor(ps, 1); ps += __shfl_xor(ps, 2); ps += __shfl_xor(ps, 4);
            pd += __shfl_xor(pd, 1); pd += __shfl_xor(pd, 2); pd += __shfl_xor(pd, 4);
            if (n < N) {
                *(float4*)(h + (size_t)n * 128 + half * 64 + 4 * o4) =
                    make_float4(acc[i][0], acc[i][1], acc[i][2], acc[i][3]);
                if ((o4 & 7) == 0) {
                    s_src[n * 4 + head] = ps;
                    s_dst[n * 4 + head] = pd;
                }
            }
        }
    }
}

// ---------------------------------------------------------------------------
// Kernel B: per-edge scores -> exp_s (stored in alpha region) + denom atomics.
// No segment-max needed: leaky-relu bounds scores to ~[-4.3, +3.5]; the
// eps in the denominator is negligible (denominator >= exp(max) term).
// ---------------------------------------------------------------------------
__global__ __launch_bounds__(256) void edge_score_kernel(
    const int* __restrict__ src, const int* __restrict__ dst,
    const float* __restrict__ rnbrw,
    const float* __restrict__ s_src, const float* __restrict__ s_dst,
    float* __restrict__ exp_out, float* __restrict__ denom, int E)
{
    int e = blockIdx.x * 256 + threadIdx.x;
    if (e >= E) return;
    int s = src[e], d = dst[e];
    float lw = __logf(rnbrw[e] + EPS);
    float4 a = *(const float4*)(s_src + s * 4);
    float4 b = *(const float4*)(s_dst + d * 4);
    float sc[4] = {a.x + b.x + lw, a.y + b.y + lw, a.z + b.z + lw, a.w + b.w + lw};
    float es[4];
#pragma unroll
    for (int hh = 0; hh < 4; ++hh) {
        float v = sc[hh];
        v = (v >= 0.f) ? v : 0.2f * v;   // leaky_relu(0.2); TEMPERATURE==1
        es[hh] = __expf(v);
    }
    *(float4*)(exp_out + (size_t)e * 4) = make_float4(es[0], es[1], es[2], es[3]);
#pragma unroll
    for (int hh = 0; hh < 4; ++hh)
        atomicAdd(denom + d * 4 + hh, es[hh]);
}

// ---------------------------------------------------------------------------
// Kernel C: alpha = exp_s / (denom[dst]+eps); out[dst] += alpha * h[src].
// 32 lanes per edge; lane j handles elements j*4..j*4+3 (head = j>>3).
// h row read is a fully-coalesced 512B burst (L3-resident 51MB table).
// ---------------------------------------------------------------------------
__global__ __launch_bounds__(256) void edge_aggr_kernel(
    const int* __restrict__ src, const int* __restrict__ dst,
    const float* __restrict__ h, const float* __restrict__ denom,
    float* __restrict__ alpha, float* __restrict__ out, int E)
{
    int gid = blockIdx.x * 256 + threadIdx.x;
    int e = gid >> 5;
    int lane = gid & 31;
    if (e >= E) return;
    int s = src[e], d = dst[e];
    int hd = lane >> 3;
    float es = alpha[(size_t)e * 4 + hd];           // exp_s (read before in-wave store)
    float den = denom[d * 4 + hd];
    float al = es / (den + EPS);
    if ((lane & 7) == 0) alpha[(size_t)e * 4 + hd] = al;
    float4 hv = *(const float4*)(h + (size_t)s * 128 + lane * 4);
    float* op = out + (size_t)d * 128 + lane * 4;
    atomicAdd(op + 0, al * hv.x);
    atomicAdd(op + 1, al * hv.y);
    atomicAdd(op + 2, al * hv.z);
    atomicAdd(op + 3, al * hv.w);
}

extern "C" void kernel_launch(void* const* d_in, const int* in_sizes, int n_in,
                              void* d_out, int out_size, void* d_ws, size_t ws_size,
                              hipStream_t stream) {
    const float* x      = (const float*)d_in[0];
    const float* W      = (const float*)d_in[1];
    const float* a_src  = (const float*)d_in[2];
    const float* a_dst  = (const float*)d_in[3];
    const int*   eidx   = (const int*)d_in[4];
    const float* rnbrw  = (const float*)d_in[5];

    const int E = in_sizes[5];           // 1600000
    const int N = in_sizes[0] / 128;     // 100000

    float* out   = (float*)d_out;                 // [N,128]
    float* alpha = out + (size_t)N * 128;         // [E,4]

    float* h     = (float*)d_ws;                  // [N,128]
    float* s_src = h + (size_t)N * 128;           // [N,4]
    float* s_dst = s_src + (size_t)N * 4;         // [N,4]
    float* denom = s_dst + (size_t)N * 4;         // [N,4]

    hipMemsetAsync(out,   0, (size_t)N * 128 * sizeof(float), stream);
    hipMemsetAsync(denom, 0, (size_t)N * 4 * sizeof(float), stream);

    int n_tiles = (N + 63) / 64;
    dim3 gridA(512, 2);
    gemm_s_kernel<<<gridA, 256, 0, stream>>>(x, W, a_src, a_dst, h, s_src, s_dst, N, n_tiles);

    const int* src = eidx;
    const int* dst = eidx + E;
    edge_score_kernel<<<(E + 255) / 256, 256, 0, stream>>>(src, dst, rnbrw, s_src, s_dst,
                                                           alpha, denom, E);
    int blocksC = (E * 32 + 255) / 256;
    edge_aggr_kernel<<<blocksC, 256, 0, stream>>>(src, dst, h, denom, alpha, out, E);
}

// Round 3
// 623.988 us; speedup vs baseline: 5.1114x; 5.1114x over previous
//
#include <hip/hip_runtime.h>

#define EPS 1e-8f

// ---------------------------------------------------------------------------
// Kernel A: h = x @ W^T (fp32, VALU) fused with per-node score projections
// ---------------------------------------------------------------------------
__global__ __launch_bounds__(256) void gemm_s_kernel(
    const float* __restrict__ x, const float* __restrict__ W,
    const float* __restrict__ a_src, const float* __restrict__ a_dst,
    float* __restrict__ h, float* __restrict__ s_src, float* __restrict__ s_dst,
    int N, int n_tiles)
{
    __shared__ float Wt[128 * 64];
    __shared__ float xt[128 * 64];

    const int t = threadIdx.x;
    const int half = blockIdx.y;
    const float* Wh = W + half * 64 * 128;

#pragma unroll
    for (int p = 0; p < 8; ++p) {
        int idx = p * 256 + t;
        int ol = (idx & 31) | ((idx >> 10) << 5);
        int k4 = (idx >> 5) & 31;
        float4 w = *(const float4*)(Wh + ol * 128 + k4 * 4);
        Wt[(4 * k4 + 0) * 64 + ol] = w.x;
        Wt[(4 * k4 + 1) * 64 + ol] = w.y;
        Wt[(4 * k4 + 2) * 64 + ol] = w.z;
        Wt[(4 * k4 + 3) * 64 + ol] = w.w;
    }
    __syncthreads();

    const int o4 = t & 15;
    const int n4g = t >> 4;
    const int head = half * 2 + (o4 >> 3);
    const float4 as = *(const float4*)(a_src + head * 32 + (o4 & 7) * 4);
    const float4 ad = *(const float4*)(a_dst + head * 32 + (o4 & 7) * 4);

    for (int tile = blockIdx.x; tile < n_tiles; tile += gridDim.x) {
        const int nbase = tile * 64;
        __syncthreads();
#pragma unroll
        for (int p = 0; p < 8; ++p) {
            int idx = p * 256 + t;
            int n = idx & 63;
            int k4 = idx >> 6;
            int ng = nbase + n;
            float4 v = make_float4(0.f, 0.f, 0.f, 0.f);
            if (ng < N) v = *(const float4*)(x + (size_t)ng * 128 + k4 * 4);
            xt[(4 * k4 + 0) * 64 + n] = v.x;
            xt[(4 * k4 + 1) * 64 + n] = v.y;
            xt[(4 * k4 + 2) * 64 + n] = v.z;
            xt[(4 * k4 + 3) * 64 + n] = v.w;
        }
        __syncthreads();

        float acc[4][4];
#pragma unroll
        for (int i = 0; i < 4; ++i)
#pragma unroll
            for (int j = 0; j < 4; ++j) acc[i][j] = 0.f;

        for (int k = 0; k < 128; ++k) {
            float4 wv = *(const float4*)(Wt + k * 64 + 4 * o4);
            float4 xv = *(const float4*)(xt + k * 64 + 4 * n4g);
            float wa[4] = {wv.x, wv.y, wv.z, wv.w};
            float xa[4] = {xv.x, xv.y, xv.z, xv.w};
#pragma unroll
            for (int i = 0; i < 4; ++i)
#pragma unroll
                for (int j = 0; j < 4; ++j) acc[i][j] += xa[i] * wa[j];
        }

#pragma unroll
        for (int i = 0; i < 4; ++i) {
            int n = nbase + 4 * n4g + i;
            float ps = acc[i][0] * as.x + acc[i][1] * as.y + acc[i][2] * as.z + acc[i][3] * as.w;
            float pd = acc[i][0] * ad.x + acc[i][1] * ad.y + acc[i][2] * ad.z + acc[i][3] * ad.w;
            ps += __shfl_xor(ps, 1); ps += __shfl_xor(ps, 2); ps += __shfl_xor(ps, 4);
            pd += __shfl_xor(pd, 1); pd += __shfl_xor(pd, 2); pd += __shfl_xor(pd, 4);
            if (n < N) {
                *(float4*)(h + (size_t)n * 128 + half * 64 + 4 * o4) =
                    make_float4(acc[i][0], acc[i][1], acc[i][2], acc[i][3]);
                if ((o4 & 7) == 0) {
                    s_src[n * 4 + head] = ps;
                    s_dst[n * 4 + head] = pd;
                }
            }
        }
    }
}

// ---------------------------------------------------------------------------
// Kernel B: per-edge exp(leaky(score)) -> expTab (alpha region). NO atomics.
// No segment-max needed: leaky-relu bounds scores; exp can't overflow.
// ---------------------------------------------------------------------------
__global__ __launch_bounds__(256) void edge_score_kernel(
    const int* __restrict__ src, const int* __restrict__ dst,
    const float* __restrict__ rnbrw,
    const float* __restrict__ s_src, const float* __restrict__ s_dst,
    float* __restrict__ exp_out, int E)
{
    int e = blockIdx.x * 256 + threadIdx.x;
    if (e >= E) return;
    int s = src[e], d = dst[e];
    float lw = __logf(rnbrw[e] + EPS);
    float4 a = *(const float4*)(s_src + s * 4);
    float4 b = *(const float4*)(s_dst + d * 4);
    float sc[4] = {a.x + b.x + lw, a.y + b.y + lw, a.z + b.z + lw, a.w + b.w + lw};
    float es[4];
#pragma unroll
    for (int hh = 0; hh < 4; ++hh) {
        float v = sc[hh];
        v = (v >= 0.f) ? v : 0.2f * v;
        es[hh] = __expf(v);
    }
    *(float4*)(exp_out + (size_t)e * 4) = make_float4(es[0], es[1], es[2], es[3]);
}

// ---------------------------------------------------------------------------
// CSR build: histogram -> 2-level exclusive scan -> scatter
// ---------------------------------------------------------------------------
__global__ __launch_bounds__(256) void hist_kernel(
    const int* __restrict__ dst, int* __restrict__ counts, int E)
{
    int e = blockIdx.x * 256 + threadIdx.x;
    if (e < E) atomicAdd(counts + dst[e], 1);
}

__global__ __launch_bounds__(256) void scan1_kernel(
    const int* __restrict__ counts, int* __restrict__ offs, int* __restrict__ bsum, int N)
{
    __shared__ int sh[256];
    int t = threadIdx.x;
    int base = blockIdx.x * 1024 + t * 4;
    int c[4];
#pragma unroll
    for (int j = 0; j < 4; ++j) c[j] = (base + j < N) ? counts[base + j] : 0;
    int tsum = c[0] + c[1] + c[2] + c[3];
    sh[t] = tsum;
    __syncthreads();
    for (int off = 1; off < 256; off <<= 1) {
        int v = (t >= off) ? sh[t - off] : 0;
        __syncthreads();
        sh[t] += v;
        __syncthreads();
    }
    int run = sh[t] - tsum;  // exclusive
    if (t == 255) bsum[blockIdx.x] = sh[255];
#pragma unroll
    for (int j = 0; j < 4; ++j) {
        if (base + j < N) { offs[base + j] = run; run += c[j]; }
    }
}

__global__ void scan2_kernel(int* __restrict__ bsum, int nb)
{
    if (threadIdx.x == 0) {
        int acc = 0;
        for (int i = 0; i < nb; ++i) { int v = bsum[i]; bsum[i] = acc; acc += v; }
    }
}

__global__ __launch_bounds__(256) void scan3_kernel(
    int* __restrict__ offs, const int* __restrict__ bsum,
    int* __restrict__ cursor, int N)
{
    int i = blockIdx.x * 256 + threadIdx.x;
    if (i >= N) return;
    int v = offs[i] + bsum[i >> 10];
    offs[i] = v;
    cursor[i] = v;
}

__global__ __launch_bounds__(256) void scatter_kernel(
    const int* __restrict__ dst, int* __restrict__ cursor,
    int* __restrict__ csr_e, int E)
{
    int e = blockIdx.x * 256 + threadIdx.x;
    if (e >= E) return;
    int pos = atomicAdd(cursor + dst[e], 1);
    csr_e[pos] = e;
}

// ---------------------------------------------------------------------------
// Kernel C: per-node aggregation, no atomics.
//   out[n] = (sum_e es_e * h[src_e]) / (sum_e es_e + EPS)
//   alpha[e,h] = es_e_h / (den_h + EPS)
// 32 lanes per node; lane l owns out elements l*4..l*4+3 (head = l>>3).
// Per-head denominators are exchanged with UNIFORM-exec shuffles before the
// divergent alpha loop (R2 bug: shfl inside divergent loop read exec-masked
// lanes -> garbage).
// ---------------------------------------------------------------------------
__global__ __launch_bounds__(256) void node_aggr_kernel(
    const int* __restrict__ src, const int* __restrict__ offs,
    const int* __restrict__ counts, const int* __restrict__ csr_e,
    const float* __restrict__ h, float* expalpha,
    float* __restrict__ out, int N)
{
    int gid = blockIdx.x * 256 + threadIdx.x;
    int n = gid >> 5;
    int l = gid & 31;
    if (n >= N) return;

    int beg = offs[n];
    int cnt = counts[n];
    int head = l >> 3;

    float4 acc = make_float4(0.f, 0.f, 0.f, 0.f);
    float den = 0.f;

    for (int base = 0; base < cnt; base += 32) {
        int m = cnt - base; if (m > 32) m = 32;
        int e_l = 0, s_l = 0;
        if (l < m) {
            e_l = csr_e[beg + base + l];
            s_l = src[e_l];
        }
        for (int i = 0; i < m; ++i) {
            int e = __shfl(e_l, i, 32);
            int s = __shfl(s_l, i, 32);
            float es = expalpha[(size_t)e * 4 + head];
            float4 hv = *(const float4*)(h + (size_t)s * 128 + l * 4);
            acc.x += es * hv.x; acc.y += es * hv.y;
            acc.z += es * hv.z; acc.w += es * hv.w;
            den += es;
        }
    }

    // all 32 lanes active here: uniform-exec exchange of per-head denominators
    float inv_h[4];
#pragma unroll
    for (int q = 0; q < 4; ++q) {
        float dq = __shfl(den, q << 3, 32);
        inv_h[q] = 1.f / (dq + EPS);
    }

    float inv = inv_h[head];
    acc.x *= inv; acc.y *= inv; acc.z *= inv; acc.w *= inv;
    *(float4*)(out + (size_t)n * 128 + l * 4) = acc;

    // alpha pass (divergent trip counts OK: only private registers used)
    for (int idx = l; idx < cnt * 4; idx += 32) {
        int i = idx >> 2;
        int hh = idx & 3;
        int e = csr_e[beg + i];
        float es = expalpha[(size_t)e * 4 + hh];
        expalpha[(size_t)e * 4 + hh] = es * inv_h[hh];
    }
}

extern "C" void kernel_launch(void* const* d_in, const int* in_sizes, int n_in,
                              void* d_out, int out_size, void* d_ws, size_t ws_size,
                              hipStream_t stream) {
    const float* x      = (const float*)d_in[0];
    const float* W      = (const float*)d_in[1];
    const float* a_src  = (const float*)d_in[2];
    const float* a_dst  = (const float*)d_in[3];
    const int*   eidx   = (const int*)d_in[4];
    const float* rnbrw  = (const float*)d_in[5];

    const int E = in_sizes[5];           // 1600000
    const int N = in_sizes[0] / 128;     // 100000

    float* out      = (float*)d_out;                 // [N,128]
    float* expalpha = out + (size_t)N * 128;         // [E,4]: exp_s then alpha

    float* h     = (float*)d_ws;                     // [N,128]
    float* s_src = h + (size_t)N * 128;              // [N,4]
    float* s_dst = s_src + (size_t)N * 4;            // [N,4]
    int* counts  = (int*)(s_dst + (size_t)N * 4);    // [N]
    int* offs    = counts + N;                       // [N]
    int* cursor  = offs + N;                         // [N]
    int* bsum    = cursor + N;                       // [128]
    int* csr_e   = bsum + 128;                       // [E]

    const int* src = eidx;
    const int* dst = eidx + E;

    hipMemsetAsync(counts, 0, (size_t)N * sizeof(int), stream);

    int n_tiles = (N + 63) / 64;
    dim3 gridA(512, 2);
    gemm_s_kernel<<<gridA, 256, 0, stream>>>(x, W, a_src, a_dst, h, s_src, s_dst, N, n_tiles);

    int eblocks = (E + 255) / 256;
    hist_kernel<<<eblocks, 256, 0, stream>>>(dst, counts, E);

    int nb = (N + 1023) / 1024;
    scan1_kernel<<<nb, 256, 0, stream>>>(counts, offs, bsum, N);
    scan2_kernel<<<1, 64, 0, stream>>>(bsum, nb);
    scan3_kernel<<<(N + 255) / 256, 256, 0, stream>>>(offs, bsum, cursor, N);

    scatter_kernel<<<eblocks, 256, 0, stream>>>(dst, cursor, csr_e, E);

    edge_score_kernel<<<eblocks, 256, 0, stream>>>(src, dst, rnbrw, s_src, s_dst,
                                                   expalpha, E);

    int ablocks = ((size_t)N * 32 + 255) / 256;
    node_aggr_kernel<<<ablocks, 256, 0, stream>>>(src, offs, counts, csr_e,
                                                  h, expalpha, out, N);
}

// Round 4
// 442.922 us; speedup vs baseline: 7.2010x; 1.4088x over previous
//
#include <hip/hip_runtime.h>

#define EPS 1e-8f

__device__ inline unsigned short f2bf(float f) {           // RNE fp32->bf16
    unsigned u = __float_as_uint(f);
    unsigned r = u + 0x7fffu + ((u >> 16) & 1u);
    return (unsigned short)(r >> 16);
}
__device__ inline float bflo(unsigned v) { return __uint_as_float(v << 16); }
__device__ inline float bfhi(unsigned v) { return __uint_as_float(v & 0xffff0000u); }

// broadcast component `head` of lane i's es4 (must be called with full group active)
__device__ inline float bsel(float4 es4, int i, int head) {
    float x = __shfl(es4.x, i, 32);
    float y = __shfl(es4.y, i, 32);
    float z = __shfl(es4.z, i, 32);
    float w = __shfl(es4.w, i, 32);
    return head == 0 ? x : head == 1 ? y : head == 2 ? z : w;
}

// ---------------------------------------------------------------------------
// Kernel A: h = x @ W^T (fp32 VALU GEMM) fused with score projections.
// h is written as bf16 (halves the aggregation gather volume).
// ---------------------------------------------------------------------------
__global__ __launch_bounds__(256) void gemm_s_kernel(
    const float* __restrict__ x, const float* __restrict__ W,
    const float* __restrict__ a_src, const float* __restrict__ a_dst,
    unsigned short* __restrict__ hb, float* __restrict__ s_src, float* __restrict__ s_dst,
    int N, int n_tiles)
{
    __shared__ float Wt[128 * 64];
    __shared__ float xt[128 * 64];

    const int t = threadIdx.x;
    const int half = blockIdx.y;
    const float* Wh = W + half * 64 * 128;

#pragma unroll
    for (int p = 0; p < 8; ++p) {
        int idx = p * 256 + t;
        int ol = (idx & 31) | ((idx >> 10) << 5);
        int k4 = (idx >> 5) & 31;
        float4 w = *(const float4*)(Wh + ol * 128 + k4 * 4);
        Wt[(4 * k4 + 0) * 64 + ol] = w.x;
        Wt[(4 * k4 + 1) * 64 + ol] = w.y;
        Wt[(4 * k4 + 2) * 64 + ol] = w.z;
        Wt[(4 * k4 + 3) * 64 + ol] = w.w;
    }
    __syncthreads();

    const int o4 = t & 15;
    const int n4g = t >> 4;
    const int head = half * 2 + (o4 >> 3);
    const float4 as = *(const float4*)(a_src + head * 32 + (o4 & 7) * 4);
    const float4 ad = *(const float4*)(a_dst + head * 32 + (o4 & 7) * 4);

    for (int tile = blockIdx.x; tile < n_tiles; tile += gridDim.x) {
        const int nbase = tile * 64;
        __syncthreads();
#pragma unroll
        for (int p = 0; p < 8; ++p) {
            int idx = p * 256 + t;
            int n = idx & 63;
            int k4 = idx >> 6;
            int ng = nbase + n;
            float4 v = make_float4(0.f, 0.f, 0.f, 0.f);
            if (ng < N) v = *(const float4*)(x + (size_t)ng * 128 + k4 * 4);
            xt[(4 * k4 + 0) * 64 + n] = v.x;
            xt[(4 * k4 + 1) * 64 + n] = v.y;
            xt[(4 * k4 + 2) * 64 + n] = v.z;
            xt[(4 * k4 + 3) * 64 + n] = v.w;
        }
        __syncthreads();

        float acc[4][4];
#pragma unroll
        for (int i = 0; i < 4; ++i)
#pragma unroll
            for (int j = 0; j < 4; ++j) acc[i][j] = 0.f;

        for (int k = 0; k < 128; ++k) {
            float4 wv = *(const float4*)(Wt + k * 64 + 4 * o4);
            float4 xv = *(const float4*)(xt + k * 64 + 4 * n4g);
            float wa[4] = {wv.x, wv.y, wv.z, wv.w};
            float xa[4] = {xv.x, xv.y, xv.z, xv.w};
#pragma unroll
            for (int i = 0; i < 4; ++i)
#pragma unroll
                for (int j = 0; j < 4; ++j) acc[i][j] += xa[i] * wa[j];
        }

#pragma unroll
        for (int i = 0; i < 4; ++i) {
            int n = nbase + 4 * n4g + i;
            float ps = acc[i][0] * as.x + acc[i][1] * as.y + acc[i][2] * as.z + acc[i][3] * as.w;
            float pd = acc[i][0] * ad.x + acc[i][1] * ad.y + acc[i][2] * ad.z + acc[i][3] * ad.w;
            ps += __shfl_xor(ps, 1); ps += __shfl_xor(ps, 2); ps += __shfl_xor(ps, 4);
            pd += __shfl_xor(pd, 1); pd += __shfl_xor(pd, 2); pd += __shfl_xor(pd, 4);
            if (n < N) {
                ushort4 hv;
                hv.x = f2bf(acc[i][0]); hv.y = f2bf(acc[i][1]);
                hv.z = f2bf(acc[i][2]); hv.w = f2bf(acc[i][3]);
                *(ushort4*)(hb + (size_t)n * 128 + half * 64 + 4 * o4) = hv;
                if ((o4 & 7) == 0) {
                    s_src[n * 4 + head] = ps;
                    s_dst[n * 4 + head] = pd;
                }
            }
        }
    }
}

// ---------------------------------------------------------------------------
// Kernel B: per-edge exp(leaky(score)) -> es_orig (alpha region of d_out),
// contiguous float4 writes. Fused dst histogram.
// No segment-max needed: leaky-relu bounds scores; exp can't overflow.
// ---------------------------------------------------------------------------
__global__ __launch_bounds__(256) void edge_score_kernel(
    const int* __restrict__ src, const int* __restrict__ dst,
    const float* __restrict__ rnbrw,
    const float* __restrict__ s_src, const float* __restrict__ s_dst,
    float* __restrict__ es_orig, int* __restrict__ counts, int E)
{
    int e = blockIdx.x * 256 + threadIdx.x;
    if (e >= E) return;
    int s = src[e], d = dst[e];
    float lw = __logf(rnbrw[e] + EPS);
    float4 a = *(const float4*)(s_src + s * 4);
    float4 b = *(const float4*)(s_dst + d * 4);
    float sc[4] = {a.x + b.x + lw, a.y + b.y + lw, a.z + b.z + lw, a.w + b.w + lw};
    float es[4];
#pragma unroll
    for (int hh = 0; hh < 4; ++hh) {
        float v = sc[hh];
        v = (v >= 0.f) ? v : 0.2f * v;
        es[hh] = __expf(v);
    }
    *(float4*)(es_orig + (size_t)e * 4) = make_float4(es[0], es[1], es[2], es[3]);
    atomicAdd(counts + d, 1);
}

// ---------------------------------------------------------------------------
// CSR build: 2-level exclusive scan + packing scatter
// ---------------------------------------------------------------------------
__global__ __launch_bounds__(256) void scan1_kernel(
    const int* __restrict__ counts, int* __restrict__ offs, int* __restrict__ bsum, int N)
{
    __shared__ int sh[256];
    int t = threadIdx.x;
    int base = blockIdx.x * 1024 + t * 4;
    int c[4];
#pragma unroll
    for (int j = 0; j < 4; ++j) c[j] = (base + j < N) ? counts[base + j] : 0;
    int tsum = c[0] + c[1] + c[2] + c[3];
    sh[t] = tsum;
    __syncthreads();
    for (int off = 1; off < 256; off <<= 1) {
        int v = (t >= off) ? sh[t - off] : 0;
        __syncthreads();
        sh[t] += v;
        __syncthreads();
    }
    int run = sh[t] - tsum;  // exclusive
    if (t == 255) bsum[blockIdx.x] = sh[255];
#pragma unroll
    for (int j = 0; j < 4; ++j) {
        if (base + j < N) { offs[base + j] = run; run += c[j]; }
    }
}

__global__ void scan2_kernel(int* __restrict__ bsum, int nb)
{
    if (threadIdx.x == 0) {
        int acc = 0;
        for (int i = 0; i < nb; ++i) { int v = bsum[i]; bsum[i] = acc; acc += v; }
    }
}

__global__ __launch_bounds__(256) void scan3_kernel(
    int* __restrict__ offs, const int* __restrict__ bsum,
    int* __restrict__ cursor, int N)
{
    int i = blockIdx.x * 256 + threadIdx.x;
    if (i >= N) return;
    int v = offs[i] + bsum[i >> 10];
    offs[i] = v;
    cursor[i] = v;
}

// packing scatter: per CSR slot store src-node, edge-id, and es4 so the
// aggregation kernel reads everything except h contiguously.
__global__ __launch_bounds__(256) void scatter_kernel(
    const int* __restrict__ src, const int* __restrict__ dst,
    const float* __restrict__ es_orig, int* __restrict__ cursor,
    int* __restrict__ csr_src, int* __restrict__ csr_eid,
    float* __restrict__ csr_es, int E)
{
    int e = blockIdx.x * 256 + threadIdx.x;
    if (e >= E) return;
    int pos = atomicAdd(cursor + dst[e], 1);
    csr_src[pos] = src[e];
    csr_eid[pos] = e;
    *(float4*)(csr_es + (size_t)pos * 4) = *(const float4*)(es_orig + (size_t)e * 4);
}

// ---------------------------------------------------------------------------
// Kernel C: per-node aggregation, no atomics, bf16 h gathers, 4-wide MLP.
//   out[n] = (sum_e es_e * h[src_e]) / (sum_e es_e + EPS)
//   alpha[e,h] = es_e_h / (den_h + EPS)
// 32 lanes per node; lane l owns out elems l*4..l*4+3 (head = l>>3).
// ---------------------------------------------------------------------------
__global__ __launch_bounds__(256) void node_aggr_kernel(
    const int* __restrict__ offs, const int* __restrict__ counts,
    const int* __restrict__ csr_src, const int* __restrict__ csr_eid,
    const float* __restrict__ csr_es,
    const unsigned short* __restrict__ hb,
    float* __restrict__ alpha, float* __restrict__ out, int N)
{
    int gid = blockIdx.x * 256 + threadIdx.x;
    int n = gid >> 5;
    int l = gid & 31;
    if (n >= N) return;

    int beg = offs[n];
    int cnt = counts[n];
    int head = l >> 3;

    float4 acc = make_float4(0.f, 0.f, 0.f, 0.f);
    float den = 0.f;

    for (int base = 0; base < cnt; base += 32) {
        int m = cnt - base; if (m > 32) m = 32;
        int sl = 0;
        float4 es4 = make_float4(0.f, 0.f, 0.f, 0.f);
        if (l < m) {
            int p = beg + base + l;
            sl = csr_src[p];
            es4 = *(const float4*)(csr_es + (size_t)p * 4);
        }
        int mr = (m + 3) & ~3;
        for (int i = 0; i < mr; i += 4) {
            int s0 = __shfl(sl, i + 0, 32);
            int s1 = __shfl(sl, i + 1, 32);
            int s2 = __shfl(sl, i + 2, 32);
            int s3 = __shfl(sl, i + 3, 32);
            uint2 v0 = *(const uint2*)(hb + (size_t)s0 * 128 + l * 4);
            uint2 v1 = *(const uint2*)(hb + (size_t)s1 * 128 + l * 4);
            uint2 v2 = *(const uint2*)(hb + (size_t)s2 * 128 + l * 4);
            uint2 v3 = *(const uint2*)(hb + (size_t)s3 * 128 + l * 4);
            float e0 = bsel(es4, i + 0, head);
            float e1 = bsel(es4, i + 1, head);
            float e2 = bsel(es4, i + 2, head);
            float e3 = bsel(es4, i + 3, head);
            acc.x += e0 * bflo(v0.x); acc.y += e0 * bfhi(v0.x);
            acc.z += e0 * bflo(v0.y); acc.w += e0 * bfhi(v0.y);
            acc.x += e1 * bflo(v1.x); acc.y += e1 * bfhi(v1.x);
            acc.z += e1 * bflo(v1.y); acc.w += e1 * bfhi(v1.y);
            acc.x += e2 * bflo(v2.x); acc.y += e2 * bfhi(v2.x);
            acc.z += e2 * bflo(v2.y); acc.w += e2 * bfhi(v2.y);
            acc.x += e3 * bflo(v3.x); acc.y += e3 * bfhi(v3.x);
            acc.z += e3 * bflo(v3.y); acc.w += e3 * bfhi(v3.y);
            den += e0 + e1 + e2 + e3;
        }
    }

    // uniform-exec exchange of per-head denominators (all 32 lanes active)
    float inv_h[4];
#pragma unroll
    for (int q = 0; q < 4; ++q) {
        float dq = __shfl(den, q << 3, 32);
        inv_h[q] = 1.f / (dq + EPS);
    }

    float inv = inv_h[head];
    acc.x *= inv; acc.y *= inv; acc.z *= inv; acc.w *= inv;
    *(float4*)(out + (size_t)n * 128 + l * 4) = acc;

    // alpha pass: contiguous CSR reads, scattered 16B writes to original order
    for (int base = 0; base < cnt; base += 32) {
        int m = cnt - base; if (m > 32) m = 32;
        if (l < m) {
            int p = beg + base + l;
            int eid = csr_eid[p];
            float4 es4 = *(const float4*)(csr_es + (size_t)p * 4);
            float4 al = make_float4(es4.x * inv_h[0], es4.y * inv_h[1],
                                    es4.z * inv_h[2], es4.w * inv_h[3]);
            *(float4*)(alpha + (size_t)eid * 4) = al;
        }
    }
}

extern "C" void kernel_launch(void* const* d_in, const int* in_sizes, int n_in,
                              void* d_out, int out_size, void* d_ws, size_t ws_size,
                              hipStream_t stream) {
    const float* x      = (const float*)d_in[0];
    const float* W      = (const float*)d_in[1];
    const float* a_src  = (const float*)d_in[2];
    const float* a_dst  = (const float*)d_in[3];
    const int*   eidx   = (const int*)d_in[4];
    const float* rnbrw  = (const float*)d_in[5];

    const int E = in_sizes[5];           // 1600000
    const int N = in_sizes[0] / 128;     // 100000

    float* out   = (float*)d_out;                    // [N,128]
    float* alpha = out + (size_t)N * 128;            // [E,4] final alpha
    float* es_orig = alpha;                          // exp table lives here first

    char* w = (char*)d_ws;
    unsigned short* hb = (unsigned short*)w;  w += (size_t)N * 128 * 2;  // h bf16
    float* s_src = (float*)w;                 w += (size_t)N * 4 * 4;
    float* s_dst = (float*)w;                 w += (size_t)N * 4 * 4;
    int* counts  = (int*)w;                   w += (size_t)N * 4;
    int* offs    = (int*)w;                   w += (size_t)N * 4;
    int* cursor  = (int*)w;                   w += (size_t)N * 4;
    int* bsum    = (int*)w;                   w += 512;
    int* csr_src = (int*)w;                   w += (size_t)E * 4;
    int* csr_eid = (int*)w;                   w += (size_t)E * 4;
    float* csr_es = (float*)w;                // [E,4]

    const int* src = eidx;
    const int* dst = eidx + E;

    hipMemsetAsync(counts, 0, (size_t)N * sizeof(int), stream);

    int n_tiles = (N + 63) / 64;
    dim3 gridA(512, 2);
    gemm_s_kernel<<<gridA, 256, 0, stream>>>(x, W, a_src, a_dst, hb, s_src, s_dst, N, n_tiles);

    int eblocks = (E + 255) / 256;
    edge_score_kernel<<<eblocks, 256, 0, stream>>>(src, dst, rnbrw, s_src, s_dst,
                                                   es_orig, counts, E);

    int nb = (N + 1023) / 1024;
    scan1_kernel<<<nb, 256, 0, stream>>>(counts, offs, bsum, N);
    scan2_kernel<<<1, 64, 0, stream>>>(bsum, nb);
    scan3_kernel<<<(N + 255) / 256, 256, 0, stream>>>(offs, bsum, cursor, N);

    scatter_kernel<<<eblocks, 256, 0, stream>>>(src, dst, es_orig, cursor,
                                                csr_src, csr_eid, csr_es, E);

    int ablocks = ((size_t)N * 32 + 255) / 256;
    node_aggr_kernel<<<ablocks, 256, 0, stream>>>(offs, counts, csr_src, csr_eid,
                                                  csr_es, hb, alpha, out, N);
}